// Round 3
// baseline (58.985 us; speedup 1.0000x reference)
//
#include <hip/hip_runtime.h>

#define D_MODEL 2048
#define D4 (D_MODEL / 4)   // 512 float4 per row

typedef float f32x4 __attribute__((ext_vector_type(4)));

// One wave per row. No LDS: W (24 KB) is re-read from global each row and
// stays L1-resident because latent is loaded nontemporally (nt hint keeps
// the streaming data from evicting W). Lanes 0..2 apply the closed-form
// diffusion blend and write.
__global__ __launch_bounds__(256) void diff_coord_kernel(
    const float* __restrict__ latent,
    const float* __restrict__ W,
    const float* __restrict__ b,
    const float* __restrict__ noise,
    const int*   __restrict__ tsteps,
    float*       __restrict__ out,
    int nrows)
{
    const int wid  = threadIdx.x >> 6;
    const int lane = threadIdx.x & 63;
    const int T    = tsteps[0];

    // x_T = p*x_0 + (1-p)*coords, p = prod_{t=1..T} t/T (affine fixed point).
    float p = 1.0f;
    for (int t = 1; t <= T; ++t) p *= (float)t / (float)T;
    const float q = 1.0f - p;

    const float bias = (lane < 3) ? b[lane] : 0.0f;

    const f32x4* W4 = reinterpret_cast<const f32x4*>(W);   // [3*512] quads
    const int nwaves = gridDim.x * 4;

    for (int row = blockIdx.x * 4 + wid; row < nrows; row += nwaves) {
        // Early noise load — latency hides under the latent loads.
        const float nz = (lane < 3) ? noise[(size_t)row * 3 + lane] : 0.0f;

        const f32x4* lat4 =
            reinterpret_cast<const f32x4*>(latent) + (size_t)row * D4;

        float a0 = 0.0f, a1 = 0.0f, a2 = 0.0f;
        #pragma unroll
        for (int kk = 0; kk < 2; ++kk) {
            #pragma unroll
            for (int k = 0; k < 4; ++k) {
                const int j = kk * 256 + k * 64 + lane;   // coalesced 1 KB/instr
                const f32x4 x  = __builtin_nontemporal_load(lat4 + j);
                const f32x4 w0 = W4[j];                   // L1-hit after first row
                const f32x4 w1 = W4[D4 + j];
                const f32x4 w2 = W4[2 * D4 + j];
                a0 += x.x * w0.x + x.y * w0.y + x.z * w0.z + x.w * w0.w;
                a1 += x.x * w1.x + x.y * w1.y + x.z * w1.z + x.w * w1.w;
                a2 += x.x * w2.x + x.y * w2.y + x.z * w2.z + x.w * w2.w;
            }
        }

        // 64-lane butterfly reduction.
        #pragma unroll
        for (int off = 32; off >= 1; off >>= 1) {
            a0 += __shfl_xor(a0, off);
            a1 += __shfl_xor(a1, off);
            a2 += __shfl_xor(a2, off);
        }

        if (lane < 3) {
            const float c = (lane == 0 ? a0 : (lane == 1 ? a1 : a2)) + bias;
            out[(size_t)row * 3 + lane] = p * nz + q * c;
        }
    }
}

extern "C" void kernel_launch(void* const* d_in, const int* in_sizes, int n_in,
                              void* d_out, int out_size, void* d_ws, size_t ws_size,
                              hipStream_t stream) {
    const float* latent = (const float*)d_in[0];
    const float* W      = (const float*)d_in[1];
    const float* b      = (const float*)d_in[2];
    const float* noise  = (const float*)d_in[3];
    const int*   tsteps = (const int*)d_in[4];
    float* out = (float*)d_out;

    const int nrows = in_sizes[0] / D_MODEL;   // B*S = 32768

    // 2048 blocks x 4 waves, grid-stride: 4 rows per wave.
    diff_coord_kernel<<<2048, 256, 0, stream>>>(latent, W, b, noise, tsteps,
                                                out, nrows);
}

// Round 4
// 44.335 us; speedup vs baseline: 1.3304x; 1.3304x over previous
//
#include <hip/hip_runtime.h>

#define D_MODEL 2048
#define D4 (D_MODEL / 4)   // 512 float4 per row

typedef float f32x4 __attribute__((ext_vector_type(4)));

// One wave per row. W (3x2048) lives in 96 VGPRs per lane-slice, loaded ONCE
// per wave before the row loop (zero per-row W traffic — neither LDS nor
// global). Accumulate in f32x4 (v_pk_fma_f32), horizontal + butterfly reduce,
// lanes 0..2 apply the closed-form diffusion blend and write.
__global__ __launch_bounds__(256) void diff_coord_kernel(
    const float* __restrict__ latent,
    const float* __restrict__ W,
    const float* __restrict__ b,
    const float* __restrict__ noise,
    const int*   __restrict__ tsteps,
    float*       __restrict__ out,
    int nrows)
{
    const int wid  = threadIdx.x >> 6;
    const int lane = threadIdx.x & 63;
    const int T    = tsteps[0];

    // x_T = p*x_0 + (1-p)*coords, p = prod_{t=1..T} t/T (affine fixed point).
    float p = 1.0f;
    for (int t = 1; t <= T; ++t) p *= (float)t / (float)T;
    const float q = 1.0f - p;

    const float bias = (lane < 3) ? b[lane] : 0.0f;

    // Load this lane's W slice into registers: quads j = k*64+lane, k=0..7,
    // for each of the 3 output rows. 24 dwordx4 per wave, once per kernel.
    const f32x4* W4 = reinterpret_cast<const f32x4*>(W);
    f32x4 w0[8], w1[8], w2[8];
    #pragma unroll
    for (int k = 0; k < 8; ++k) {
        const int j = k * 64 + lane;
        w0[k] = W4[j];
        w1[k] = W4[D4 + j];
        w2[k] = W4[2 * D4 + j];
    }

    const int nwaves = gridDim.x * 4;
    for (int row = blockIdx.x * 4 + wid; row < nrows; row += nwaves) {
        // Early noise load — hides under the latent load wait.
        const float nz = (lane < 3) ? noise[(size_t)row * 3 + lane] : 0.0f;

        const f32x4* lat4 =
            reinterpret_cast<const f32x4*>(latent) + (size_t)row * D4;

        f32x4 s0 = {0.f, 0.f, 0.f, 0.f};
        f32x4 s1 = {0.f, 0.f, 0.f, 0.f};
        f32x4 s2 = {0.f, 0.f, 0.f, 0.f};
        #pragma unroll
        for (int k = 0; k < 8; ++k) {
            const f32x4 x = lat4[k * 64 + lane];   // coalesced 1 KB/instr
            s0 += x * w0[k];                       // v_pk_fma_f32 x2
            s1 += x * w1[k];
            s2 += x * w2[k];
        }
        float a0 = (s0.x + s0.y) + (s0.z + s0.w);
        float a1 = (s1.x + s1.y) + (s1.z + s1.w);
        float a2 = (s2.x + s2.y) + (s2.z + s2.w);

        // 64-lane butterfly (xor 1/2/4/8 lower to DPP; 16/32 to ds_permute).
        #pragma unroll
        for (int off = 32; off >= 1; off >>= 1) {
            a0 += __shfl_xor(a0, off);
            a1 += __shfl_xor(a1, off);
            a2 += __shfl_xor(a2, off);
        }

        if (lane < 3) {
            const float c = (lane == 0 ? a0 : (lane == 1 ? a1 : a2)) + bias;
            out[(size_t)row * 3 + lane] = p * nz + q * c;
        }
    }
}

extern "C" void kernel_launch(void* const* d_in, const int* in_sizes, int n_in,
                              void* d_out, int out_size, void* d_ws, size_t ws_size,
                              hipStream_t stream) {
    const float* latent = (const float*)d_in[0];
    const float* W      = (const float*)d_in[1];
    const float* b      = (const float*)d_in[2];
    const float* noise  = (const float*)d_in[3];
    const int*   tsteps = (const int*)d_in[4];
    float* out = (float*)d_out;

    const int nrows = in_sizes[0] / D_MODEL;   // B*S = 32768

    // 2048 blocks x 4 waves, grid-stride: exactly 4 rows per wave.
    diff_coord_kernel<<<2048, 256, 0, stream>>>(latent, W, b, noise, tsteps,
                                                out, nrows);
}

// Round 5
// 43.762 us; speedup vs baseline: 1.3479x; 1.0131x over previous
//
#include <hip/hip_runtime.h>

#define D_MODEL 2048
#define D4 (D_MODEL / 4)   // 512 float4 per row
#define RPW 4              // rows per wave (nrows == total_waves * RPW)

typedef float f32x4 __attribute__((ext_vector_type(4)));

// One wave handles 4 rows, hand-software-pipelined: row r+1's 8 dwordx4 loads
// are issued before row r's FMA+reduction, so the reduction tail hides under
// HBM latency. W (3x2048) lives in 96 VGPRs, loaded once per wave. Reduction:
// butterfly 1..8 (DPP-speed) on all 3 sums, then lane&3 selects one value for
// the two expensive cross-group steps (16, 32).
__global__ __launch_bounds__(256) void diff_coord_kernel(
    const float* __restrict__ latent,
    const float* __restrict__ W,
    const float* __restrict__ b,
    const float* __restrict__ noise,
    const int*   __restrict__ tsteps,
    float*       __restrict__ out,
    int nrows)
{
    const int wid  = threadIdx.x >> 6;
    const int lane = threadIdx.x & 63;
    const int T    = tsteps[0];

    // x_T = p*x_0 + (1-p)*coords, p = prod_{t=1..T} t/T (affine fixed point).
    float p = 1.0f;
    for (int t = 1; t <= T; ++t) p *= (float)t / (float)T;
    const float q = 1.0f - p;

    const float bias = (lane < 3) ? b[lane] : 0.0f;

    const int gw = blockIdx.x * 4 + wid;   // global wave id: 0..8191
    const int nw = gridDim.x * 4;          // total waves: 8192

    // W slice in registers: 24 dwordx4 per lane, once per wave.
    const f32x4* W4 = reinterpret_cast<const f32x4*>(W);
    f32x4 w0[8], w1[8], w2[8];
    #pragma unroll
    for (int k = 0; k < 8; ++k) {
        const int j = k * 64 + lane;
        w0[k] = W4[j];
        w1[k] = W4[D4 + j];
        w2[k] = W4[2 * D4 + j];
    }

    // Preload noise for all rows this wave owns.
    float nz[RPW];
    #pragma unroll
    for (int r = 0; r < RPW; ++r) {
        const int row = gw + r * nw;
        nz[r] = (lane < 3 && row < nrows) ? noise[(size_t)row * 3 + lane] : 0.0f;
    }

    const f32x4* lat = reinterpret_cast<const f32x4*>(latent);

    // Prologue: load row 0.
    f32x4 cur[8];
    {
        const f32x4* l0 = lat + (size_t)gw * D4;
        #pragma unroll
        for (int k = 0; k < 8; ++k) cur[k] = l0[k * 64 + lane];
    }

    #pragma unroll
    for (int r = 0; r < RPW; ++r) {
        const int row = gw + r * nw;

        // Issue next row's loads BEFORE touching cur — reduction tail of this
        // row overlaps their HBM latency.
        f32x4 nxt[8];
        if (r + 1 < RPW) {
            const f32x4* ln = lat + (size_t)(row + nw) * D4;
            #pragma unroll
            for (int k = 0; k < 8; ++k) nxt[k] = ln[k * 64 + lane];
        }

        f32x4 s0 = {0.f, 0.f, 0.f, 0.f};
        f32x4 s1 = {0.f, 0.f, 0.f, 0.f};
        f32x4 s2 = {0.f, 0.f, 0.f, 0.f};
        #pragma unroll
        for (int k = 0; k < 8; ++k) {
            s0 += cur[k] * w0[k];   // v_pk_fma_f32 x2
            s1 += cur[k] * w1[k];
            s2 += cur[k] * w2[k];
        }
        float a0 = (s0.x + s0.y) + (s0.z + s0.w);
        float a1 = (s1.x + s1.y) + (s1.z + s1.w);
        float a2 = (s2.x + s2.y) + (s2.z + s2.w);

        // Intra-16-group butterfly (DPP-speed) on all three sums.
        #pragma unroll
        for (int off = 1; off <= 8; off <<= 1) {
            a0 += __shfl_xor(a0, off);
            a1 += __shfl_xor(a1, off);
            a2 += __shfl_xor(a2, off);
        }
        // Every lane now holds its group's S0,S1,S2. Route one value per lane
        // (lane0->a0, lane1->a1, lane2->a2) through the 2 cross-group steps.
        const int sel = lane & 3;
        float v = (sel == 0) ? a0 : ((sel == 1) ? a1 : a2);
        v += __shfl_xor(v, 16);
        v += __shfl_xor(v, 32);

        if (lane < 3 && row < nrows) {
            out[(size_t)row * 3 + lane] = p * nz[r] + q * (v + bias);
        }

        if (r + 1 < RPW) {
            #pragma unroll
            for (int k = 0; k < 8; ++k) cur[k] = nxt[k];
        }
    }
}

extern "C" void kernel_launch(void* const* d_in, const int* in_sizes, int n_in,
                              void* d_out, int out_size, void* d_ws, size_t ws_size,
                              hipStream_t stream) {
    const float* latent = (const float*)d_in[0];
    const float* W      = (const float*)d_in[1];
    const float* b      = (const float*)d_in[2];
    const float* noise  = (const float*)d_in[3];
    const int*   tsteps = (const int*)d_in[4];
    float* out = (float*)d_out;

    const int nrows = in_sizes[0] / D_MODEL;   // B*S = 32768

    // 2048 blocks x 4 waves = 8192 waves x RPW(=4) rows = 32768 rows.
    diff_coord_kernel<<<2048, 256, 0, stream>>>(latent, W, b, noise, tsteps,
                                                out, nrows);
}